// Round 4
// baseline (290.962 us; speedup 1.0000x reference)
//
#include <hip/hip_runtime.h>
#include <cstdint>

typedef unsigned short ushort_t;
typedef __bf16 bf16x8 __attribute__((ext_vector_type(8)));
typedef ushort_t u16x8 __attribute__((ext_vector_type(8)));
typedef float f32x4 __attribute__((ext_vector_type(4)));
typedef uint32_t u32x4 __attribute__((ext_vector_type(4)));

#define RMS_EPS 1.1920928955078125e-07f
// B=8 T=4096 C=256 Wh=1024 E=8 K=2 ; tokens NT=32768, pairs NP=65536

__device__ __forceinline__ ushort_t f2bf(float f) {
  uint32_t u = __builtin_bit_cast(uint32_t, f);
  u += 0x7fffu + ((u >> 16) & 1u);   // RNE
  return (ushort_t)(u >> 16);
}

__device__ __forceinline__ void g2l16(const ushort_t* g, ushort_t* l) {
  __builtin_amdgcn_global_load_lds(
      (const __attribute__((address_space(1))) uint32_t*)g,
      (__attribute__((address_space(3))) uint32_t*)l, 16, 0, 0);
}

// ---- RMSNorm + cast to bf16: one wave per token ----
__global__ void rmsnorm_cast(const float* __restrict__ x, const float* __restrict__ w,
                             ushort_t* __restrict__ xn) {
  int token = blockIdx.x * 4 + (threadIdx.x >> 6);
  int lane = threadIdx.x & 63;
  const float4* row = reinterpret_cast<const float4*>(x + (size_t)token * 256);
  float4 v = row[lane];
  float s = v.x * v.x + v.y * v.y + v.z * v.z + v.w * v.w;
#pragma unroll
  for (int off = 1; off < 64; off <<= 1) s += __shfl_xor(s, off);
  float inv = rsqrtf(s * (1.0f / 256.0f) + RMS_EPS);
  const float4* wr = reinterpret_cast<const float4*>(w);
  float4 wv = wr[lane];
  ushort4 o;
  o.x = f2bf(v.x * inv * wv.x);
  o.y = f2bf(v.y * inv * wv.y);
  o.z = f2bf(v.z * inv * wv.z);
  o.w = f2bf(v.w * inv * wv.w);
  *reinterpret_cast<ushort4*>(xn + (size_t)token * 256 + lane * 4) = o;
}

// ---- pack W1/W2 into MFMA B-fragment order via LDS tile (coalesced) ----
__global__ __launch_bounds__(256) void pack_w(const float* __restrict__ W1,
                                              const float* __restrict__ W2,
                                              ushort_t* __restrict__ w1f,
                                              ushort_t* __restrict__ w2f) {
  __shared__ ushort_t tile[64][130];
  int b = blockIdx.x;
  int isW2 = b >= 256;
  const float* src; ushort_t* dst; int e, kt, wt, rs;
  if (!isW2) { e = b >> 5; kt = (b >> 3) & 3; wt = b & 7; src = W1; dst = w1f; rs = 1024; }
  else { b -= 256; e = b >> 5; kt = (b >> 1) & 15; wt = b & 1; src = W2; dst = w2f; rs = 256; }
  int k0 = kt * 64, c0 = wt * 128;
  const float* sb = src + ((size_t)e << 18) + (size_t)k0 * rs + c0;
  int t = threadIdx.x;
#pragma unroll
  for (int i = 0; i < 8; ++i) {
    int f = i * 1024 + t * 4;
    int r = f >> 7, c = f & 127;
    float4 v = *reinterpret_cast<const float4*>(sb + (size_t)r * rs + c);
    ushort2 lo, hi;
    lo.x = f2bf(v.x); lo.y = f2bf(v.y); hi.x = f2bf(v.z); hi.y = f2bf(v.w);
    *reinterpret_cast<ushort2*>(&tile[r][c]) = lo;
    *reinterpret_cast<ushort2*>(&tile[r][c + 2]) = hi;
  }
  __syncthreads();
  int lane = t & 63, l16 = lane & 15, quad = lane >> 4;
#pragma unroll
  for (int p = 0; p < 4; ++p) {
    int u = p * 256 + t;
    int kk2 = (u >> 9) & 1;
    int rr = kk2 * 32 + quad * 8;
    u16x8 o;
    size_t U;
    if (!isW2) {
      int nt = (u >> 6) & 1, chL = (u >> 7) & 3;
      int cc = chL * 32 + nt * 16 + l16;
#pragma unroll
      for (int j = 0; j < 8; ++j) o[j] = tile[rr + j][cc];
      U = ((size_t)e * 32768) + (size_t)(wt * 4 + chL) * 1024 + (kt * 2 + kk2) * 128 + nt * 64 + lane;
    } else {
      int ntL = (u >> 6) & 7;
      int cc = ntL * 16 + l16;
#pragma unroll
      for (int j = 0; j < 8; ++j) o[j] = tile[rr + j][cc];
      U = ((size_t)e * 32768) + (size_t)(kt * 2 + kk2) * 1024 + (wt * 8 + ntL) * 64 + lane;
    }
    *reinterpret_cast<u16x8*>(dst + U * 8) = o;
  }
}

// ---- route (t,k) pairs into per-expert lists ----
__global__ void route_pairs(const int* __restrict__ eids, int* __restrict__ cnt,
                            int* __restrict__ lists) {
  __shared__ int lcnt[8], lbase[8];
  int tid = threadIdx.x;
  if (tid < 8) lcnt[tid] = 0;
  __syncthreads();
  int p = blockIdx.x * 256 + tid;
  int e = eids[p];
  int lpos = atomicAdd(&lcnt[e], 1);
  __syncthreads();
  if (tid < 8) lbase[tid] = atomicAdd(&cnt[tid], lcnt[tid]);
  __syncthreads();
  lists[e * 65536 + lbase[e] + lpos] = p;
}

// ---- fused expert MLP ----
// 128 pairs/block, 4 waves x 32 rows. W1 double-buffered, W2 single-buffered
// (staged after bottom sync, overlapping next chunk's GEMM1). Regs trimmed to
// fit 2 waves/SIMD (amdgpu_waves_per_eu(2)); LDS 59.9 KB -> 2 blocks/CU.
__global__ __launch_bounds__(256, 2)
__attribute__((amdgpu_waves_per_eu(2)))
void moe_mlp(
    const ushort_t* __restrict__ xn,   // [32768][256] bf16
    const ushort_t* __restrict__ w1f,  // [8][32][16][64][8]
    const ushort_t* __restrict__ w2f,  // [8][32][16][64][8]
    const float* __restrict__ b1,      // [8][1024]
    const float* __restrict__ b2,      // [8][256]
    const int* __restrict__ cnt,       // [8]
    const int* __restrict__ lists,     // [8][65536]
    float* __restrict__ out)           // [65536][256]
{
  __shared__ __align__(16) ushort_t w1b[2][8192];     // 32 KB
  __shared__ __align__(16) ushort_t w2b[8192];        // 16 KB (single buf)
  __shared__ __align__(16) ushort_t hlds[4][32][40];  // 10 KB wave-private h
  __shared__ int prs[128];

  int flat = blockIdx.x;
  int e = -1, tile = 0, accum = 0, n_e = 0;
#pragma unroll
  for (int i = 0; i < 8; ++i) {
    int c = cnt[i];
    int t = (c + 127) >> 7;
    if (e < 0 && flat < accum + t) { e = i; tile = flat - accum; n_e = c; }
    accum += t;
  }
  if (e < 0) return;
  int start = tile * 128;

  int tid = threadIdx.x;
  if (tid < 128) {
    int idx = start + tid;
    prs[tid] = (idx < n_e) ? lists[e * 65536 + idx] : lists[e * 65536];
  }

  const ushort_t* w1e = w1f + ((size_t)e << 18);
  const ushort_t* w2e = w2f + ((size_t)e << 18);
  int wave = tid >> 6, lane = tid & 63, l16 = lane & 15, quad = lane >> 4;

  // stage chunk 0 (W1 -> buf0, W2 -> single buf)
#pragma unroll
  for (int j = 0; j < 4; ++j) {
    int p = j * 4 + wave;
    g2l16(w1e + p * 512 + lane * 8, &w1b[0][p * 512]);
    g2l16(w2e + p * 512 + lane * 8, &w2b[p * 512]);
  }
  __syncthreads();  // prs visible + stage(0) drained

  // A fragments: 2 m-tiles x full K=256, resident (64 VGPR)
  bf16x8 afr[2][8];
#pragma unroll
  for (int mt = 0; mt < 2; ++mt) {
    int tok = prs[wave * 32 + mt * 16 + l16] >> 1;
    const u32x4* arow = reinterpret_cast<const u32x4*>(xn + (size_t)tok * 256);
#pragma unroll
    for (int kk = 0; kk < 8; ++kk)
      afr[mt][kk] = __builtin_bit_cast(bf16x8, arow[kk * 4 + quad]);
  }

  f32x4 acc[2][16];
#pragma unroll
  for (int mt = 0; mt < 2; ++mt)
#pragma unroll
    for (int ct = 0; ct < 16; ++ct) acc[mt][ct] = (f32x4){0.f, 0.f, 0.f, 0.f};

  const float* b1e = b1 + e * 1024;
  ushort_t* hl = &hlds[wave][0][0];

  for (int ch = 0; ch < 32; ++ch) {
    int cur = ch & 1;
    if (ch) __syncthreads();  // W1(ch)+W2(ch) staged & visible
    if (ch + 1 < 32) {
      const ushort_t* n1 = w1e + (ch + 1) * 8192;
#pragma unroll
      for (int j = 0; j < 4; ++j) {
        int p = j * 4 + wave;
        g2l16(n1 + p * 512 + lane * 8, &w1b[cur ^ 1][p * 512]);
      }
    }
    const ushort_t* l1 = w1b[cur];
    int w0 = ch * 32;

    // GEMM1 nt=0 then GELU (h live = 8 regs), then nt=1
    f32x4 ha, hb;
    ha = (f32x4){0.f, 0.f, 0.f, 0.f};
    hb = (f32x4){0.f, 0.f, 0.f, 0.f};
#pragma unroll
    for (int kk = 0; kk < 8; ++kk) {
      bf16x8 bA = *reinterpret_cast<const bf16x8*>(l1 + ((kk * 2 + 0) * 64 + lane) * 8);
      ha = __builtin_amdgcn_mfma_f32_16x16x32_bf16(afr[0][kk], bA, ha, 0, 0, 0);
      hb = __builtin_amdgcn_mfma_f32_16x16x32_bf16(afr[1][kk], bA, hb, 0, 0, 0);
    }
    {
      float bias0 = b1e[w0 + l16];
#pragma unroll
      for (int r = 0; r < 4; ++r) {
        float v = ha[r] + bias0;
        float u_ = (0.044715f * v * v) * v + v;
        float tq = __expf(-1.5957691216057308f * u_);
        hl[(quad * 4 + r) * 40 + l16] = f2bf(v * __builtin_amdgcn_rcpf(1.0f + tq));
        float v2 = hb[r] + bias0;
        float u2 = (0.044715f * v2 * v2) * v2 + v2;
        float tq2 = __expf(-1.5957691216057308f * u2);
        hl[(16 + quad * 4 + r) * 40 + l16] = f2bf(v2 * __builtin_amdgcn_rcpf(1.0f + tq2));
      }
    }
    ha = (f32x4){0.f, 0.f, 0.f, 0.f};
    hb = (f32x4){0.f, 0.f, 0.f, 0.f};
#pragma unroll
    for (int kk = 0; kk < 8; ++kk) {
      bf16x8 bB = *reinterpret_cast<const bf16x8*>(l1 + ((kk * 2 + 1) * 64 + lane) * 8);
      ha = __builtin_amdgcn_mfma_f32_16x16x32_bf16(afr[0][kk], bB, ha, 0, 0, 0);
      hb = __builtin_amdgcn_mfma_f32_16x16x32_bf16(afr[1][kk], bB, hb, 0, 0, 0);
    }
    {
      float bias1 = b1e[w0 + 16 + l16];
#pragma unroll
      for (int r = 0; r < 4; ++r) {
        float v = ha[r] + bias1;
        float u_ = (0.044715f * v * v) * v + v;
        float tq = __expf(-1.5957691216057308f * u_);
        hl[(quad * 4 + r) * 40 + 16 + l16] = f2bf(v * __builtin_amdgcn_rcpf(1.0f + tq));
        float v2 = hb[r] + bias1;
        float u2 = (0.044715f * v2 * v2) * v2 + v2;
        float tq2 = __expf(-1.5957691216057308f * u2);
        hl[(16 + quad * 4 + r) * 40 + 16 + l16] = f2bf(v2 * __builtin_amdgcn_rcpf(1.0f + tq2));
      }
    }
    bf16x8 a2_0 = *reinterpret_cast<const bf16x8*>(hl + l16 * 40 + quad * 8);
    bf16x8 a2_1 = *reinterpret_cast<const bf16x8*>(hl + (16 + l16) * 40 + quad * 8);

    // GEMM2: y[32 rows x 256] += h[32 x 32] @ W2chunk[32 x 256]
#pragma unroll
    for (int ct = 0; ct < 16; ++ct) {
      bf16x8 b = *reinterpret_cast<const bf16x8*>(w2b + (ct * 64 + lane) * 8);
      acc[0][ct] = __builtin_amdgcn_mfma_f32_16x16x32_bf16(a2_0, b, acc[0][ct], 0, 0, 0);
      acc[1][ct] = __builtin_amdgcn_mfma_f32_16x16x32_bf16(a2_1, b, acc[1][ct], 0, 0, 0);
    }
    __syncthreads();  // all waves done reading w2b
    if (ch + 1 < 32) {
      const ushort_t* n2 = w2e + (ch + 1) * 8192;
#pragma unroll
      for (int j = 0; j < 4; ++j) {
        int p = j * 4 + wave;
        g2l16(n2 + p * 512 + lane * 8, &w2b[p * 512]);
      }
    }
  }

  // epilogue: +b2, masked scatter store
  const float* b2e = b2 + e * 256;
  float bl[16];
#pragma unroll
  for (int ct = 0; ct < 16; ++ct) bl[ct] = b2e[ct * 16 + l16];
#pragma unroll
  for (int mt = 0; mt < 2; ++mt) {
#pragma unroll
    for (int r = 0; r < 4; ++r) {
      int m = wave * 32 + mt * 16 + quad * 4 + r;
      if (start + m < n_e) {
        float* orow = out + (size_t)prs[m] * 256;
#pragma unroll
        for (int ct = 0; ct < 16; ++ct)
          orow[ct * 16 + l16] = acc[mt][ct][r] + bl[ct];
      }
    }
  }
}

extern "C" void kernel_launch(void* const* d_in, const int* in_sizes, int n_in,
                              void* d_out, int out_size, void* d_ws, size_t ws_size,
                              hipStream_t stream) {
  const float* x  = (const float*)d_in[0];
  const float* rw = (const float*)d_in[1];
  const float* W1 = (const float*)d_in[2];
  const float* b1 = (const float*)d_in[3];
  const float* W2 = (const float*)d_in[4];
  const float* b2 = (const float*)d_in[5];
  const int* eids = (const int*)d_in[6];
  float* out = (float*)d_out;

  char* ws = (char*)d_ws;
  ushort_t* xn  = (ushort_t*)(ws);              // 16,777,216 B
  ushort_t* w1f = (ushort_t*)(ws + 16777216);   //  4,194,304 B
  ushort_t* w2f = (ushort_t*)(ws + 20971520);   //  4,194,304 B
  int* cnt      = (int*)(ws + 25165824);        //  256 B (8 used)
  int* lists    = (int*)(ws + 25166080);        //  2,097,152 B

  hipMemsetAsync(cnt, 0, 8 * sizeof(int), stream);
  rmsnorm_cast<<<8192, 256, 0, stream>>>(x, rw, xn);
  pack_w<<<512, 256, 0, stream>>>(W1, W2, w1f, w2f);
  route_pairs<<<256, 256, 0, stream>>>(eids, cnt, lists);
  moe_mlp<<<519, 256, 0, stream>>>(xn, w1f, w2f, b1, b2, cnt, lists, out);
}

// Round 5
// 257.595 us; speedup vs baseline: 1.1295x; 1.1295x over previous
//
#include <hip/hip_runtime.h>
#include <cstdint>

typedef unsigned short ushort_t;
typedef __bf16 bf16x8 __attribute__((ext_vector_type(8)));
typedef ushort_t u16x8 __attribute__((ext_vector_type(8)));
typedef float f32x4 __attribute__((ext_vector_type(4)));
typedef uint32_t u32x4 __attribute__((ext_vector_type(4)));

#define RMS_EPS 1.1920928955078125e-07f
// B=8 T=4096 C=256 Wh=1024 E=8 K=2 ; tokens NT=32768, pairs NP=65536

__device__ __forceinline__ ushort_t f2bf(float f) {
  uint32_t u = __builtin_bit_cast(uint32_t, f);
  u += 0x7fffu + ((u >> 16) & 1u);   // RNE
  return (ushort_t)(u >> 16);
}

__device__ __forceinline__ void g2l16(const ushort_t* g, ushort_t* l) {
  __builtin_amdgcn_global_load_lds(
      (const __attribute__((address_space(1))) uint32_t*)g,
      (__attribute__((address_space(3))) uint32_t*)l, 16, 0, 0);
}

// ---- RMSNorm + cast to bf16: one wave per token ----
__global__ void rmsnorm_cast(const float* __restrict__ x, const float* __restrict__ w,
                             ushort_t* __restrict__ xn) {
  int token = blockIdx.x * 4 + (threadIdx.x >> 6);
  int lane = threadIdx.x & 63;
  const float4* row = reinterpret_cast<const float4*>(x + (size_t)token * 256);
  float4 v = row[lane];
  float s = v.x * v.x + v.y * v.y + v.z * v.z + v.w * v.w;
#pragma unroll
  for (int off = 1; off < 64; off <<= 1) s += __shfl_xor(s, off);
  float inv = rsqrtf(s * (1.0f / 256.0f) + RMS_EPS);
  const float4* wr = reinterpret_cast<const float4*>(w);
  float4 wv = wr[lane];
  ushort4 o;
  o.x = f2bf(v.x * inv * wv.x);
  o.y = f2bf(v.y * inv * wv.y);
  o.z = f2bf(v.z * inv * wv.z);
  o.w = f2bf(v.w * inv * wv.w);
  *reinterpret_cast<ushort4*>(xn + (size_t)token * 256 + lane * 4) = o;
}

// ---- pack W1/W2 into MFMA B-fragment order via LDS tile (coalesced) ----
__global__ __launch_bounds__(256) void pack_w(const float* __restrict__ W1,
                                              const float* __restrict__ W2,
                                              ushort_t* __restrict__ w1f,
                                              ushort_t* __restrict__ w2f) {
  __shared__ ushort_t tile[64][130];
  int b = blockIdx.x;
  int isW2 = b >= 256;
  const float* src; ushort_t* dst; int e, kt, wt, rs;
  if (!isW2) { e = b >> 5; kt = (b >> 3) & 3; wt = b & 7; src = W1; dst = w1f; rs = 1024; }
  else { b -= 256; e = b >> 5; kt = (b >> 1) & 15; wt = b & 1; src = W2; dst = w2f; rs = 256; }
  int k0 = kt * 64, c0 = wt * 128;
  const float* sb = src + ((size_t)e << 18) + (size_t)k0 * rs + c0;
  int t = threadIdx.x;
#pragma unroll
  for (int i = 0; i < 8; ++i) {
    int f = i * 1024 + t * 4;
    int r = f >> 7, c = f & 127;
    float4 v = *reinterpret_cast<const float4*>(sb + (size_t)r * rs + c);
    ushort2 lo, hi;
    lo.x = f2bf(v.x); lo.y = f2bf(v.y); hi.x = f2bf(v.z); hi.y = f2bf(v.w);
    *reinterpret_cast<ushort2*>(&tile[r][c]) = lo;
    *reinterpret_cast<ushort2*>(&tile[r][c + 2]) = hi;
  }
  __syncthreads();
  int lane = t & 63, l16 = lane & 15, quad = lane >> 4;
#pragma unroll
  for (int p = 0; p < 4; ++p) {
    int u = p * 256 + t;
    int kk2 = (u >> 9) & 1;
    int rr = kk2 * 32 + quad * 8;
    u16x8 o;
    size_t U;
    if (!isW2) {
      int nt = (u >> 6) & 1, chL = (u >> 7) & 3;
      int cc = chL * 32 + nt * 16 + l16;
#pragma unroll
      for (int j = 0; j < 8; ++j) o[j] = tile[rr + j][cc];
      U = ((size_t)e * 32768) + (size_t)(wt * 4 + chL) * 1024 + (kt * 2 + kk2) * 128 + nt * 64 + lane;
    } else {
      int ntL = (u >> 6) & 7;
      int cc = ntL * 16 + l16;
#pragma unroll
      for (int j = 0; j < 8; ++j) o[j] = tile[rr + j][cc];
      U = ((size_t)e * 32768) + (size_t)(kt * 2 + kk2) * 1024 + (wt * 8 + ntL) * 64 + lane;
    }
    *reinterpret_cast<u16x8*>(dst + U * 8) = o;
  }
}

// ---- route (t,k) pairs into per-expert lists ----
__global__ void route_pairs(const int* __restrict__ eids, int* __restrict__ cnt,
                            int* __restrict__ lists) {
  __shared__ int lcnt[8], lbase[8];
  int tid = threadIdx.x;
  if (tid < 8) lcnt[tid] = 0;
  __syncthreads();
  int p = blockIdx.x * 256 + tid;
  int e = eids[p];
  int lpos = atomicAdd(&lcnt[e], 1);
  __syncthreads();
  if (tid < 8) lbase[tid] = atomicAdd(&cnt[tid], lcnt[tid]);
  __syncthreads();
  lists[e * 65536 + lbase[e] + lpos] = p;
}

// ---- fused expert MLP ----
// 128 pairs/block, 8 waves x 16 rows (512 threads). Small per-wave tile:
// acc[16]=64 AGPR + afr[8]=32 VGPR -> combined ~160-180 regs -> 2-3 waves/SIMD.
// W1+W2 double-buffered (global_load_lds w16), ONE barrier per chunk.
__global__ __launch_bounds__(512, 2) void moe_mlp(
    const ushort_t* __restrict__ xn,   // [32768][256] bf16
    const ushort_t* __restrict__ w1f,  // [8][32][16][64][8]
    const ushort_t* __restrict__ w2f,  // [8][32][16][64][8]
    const float* __restrict__ b1,      // [8][1024]
    const float* __restrict__ b2,      // [8][256]
    const int* __restrict__ cnt,       // [8]
    const int* __restrict__ lists,     // [8][65536]
    float* __restrict__ out)           // [65536][256]
{
  __shared__ __align__(16) ushort_t w1b[2][8192];     // 32 KB
  __shared__ __align__(16) ushort_t w2b[2][8192];     // 32 KB
  __shared__ __align__(16) ushort_t hlds[8][16][40];  // 10 KB wave-private h
  __shared__ int prs[128];
  // total 76,288 B -> 2 blocks/CU (152.6 <= 160 KB)

  int flat = blockIdx.x;
  int e = -1, tile = 0, accum = 0, n_e = 0;
#pragma unroll
  for (int i = 0; i < 8; ++i) {
    int c = cnt[i];
    int t = (c + 127) >> 7;
    if (e < 0 && flat < accum + t) { e = i; tile = flat - accum; n_e = c; }
    accum += t;
  }
  if (e < 0) return;
  int start = tile * 128;

  int tid = threadIdx.x;
  if (tid < 128) {
    int idx = start + tid;
    prs[tid] = (idx < n_e) ? lists[e * 65536 + idx] : lists[e * 65536];
  }

  const ushort_t* w1e = w1f + ((size_t)e << 18);
  const ushort_t* w2e = w2f + ((size_t)e << 18);
  int wave = tid >> 6, lane = tid & 63, l16 = lane & 15, quad = lane >> 4;

  // stage chunk 0 into buffer 0 (8 waves: 2 units each per matrix)
#pragma unroll
  for (int j = 0; j < 2; ++j) {
    int p = j * 8 + wave;
    g2l16(w1e + p * 512 + lane * 8, &w1b[0][p * 512]);
    g2l16(w2e + p * 512 + lane * 8, &w2b[0][p * 512]);
  }
  __syncthreads();  // prs visible + stage(0) drained

  // A fragments: 16 rows x full K=256, resident (32 VGPR)
  bf16x8 afr[8];
  {
    int tok = prs[wave * 16 + l16] >> 1;
    const u32x4* arow = reinterpret_cast<const u32x4*>(xn + (size_t)tok * 256);
#pragma unroll
    for (int kk = 0; kk < 8; ++kk)
      afr[kk] = __builtin_bit_cast(bf16x8, arow[kk * 4 + quad]);
  }

  f32x4 acc[16];
#pragma unroll
  for (int ct = 0; ct < 16; ++ct) acc[ct] = (f32x4){0.f, 0.f, 0.f, 0.f};

  const float* b1e = b1 + e * 1024;
  ushort_t* hl = &hlds[wave][0][0];

  for (int ch = 0; ch < 32; ++ch) {
    int cur = ch & 1;
    if (ch) __syncthreads();  // stage(ch) complete+visible; all waves done with buf^1
    if (ch + 1 < 32) {
      const ushort_t* n1 = w1e + (ch + 1) * 8192;
      const ushort_t* n2 = w2e + (ch + 1) * 8192;
#pragma unroll
      for (int j = 0; j < 2; ++j) {
        int p = j * 8 + wave;
        g2l16(n1 + p * 512 + lane * 8, &w1b[cur ^ 1][p * 512]);
        g2l16(n2 + p * 512 + lane * 8, &w2b[cur ^ 1][p * 512]);
      }
    }
    const ushort_t* l1 = w1b[cur];
    const ushort_t* l2 = w2b[cur];
    int w0 = ch * 32;

    // GEMM1 nt=0 (8 MFMA) -> GELU -> nt=1 -> GELU (h live = 4 regs each)
    f32x4 ha = (f32x4){0.f, 0.f, 0.f, 0.f};
#pragma unroll
    for (int kk = 0; kk < 8; ++kk) {
      bf16x8 bA = *reinterpret_cast<const bf16x8*>(l1 + ((kk * 2 + 0) * 64 + lane) * 8);
      ha = __builtin_amdgcn_mfma_f32_16x16x32_bf16(afr[kk], bA, ha, 0, 0, 0);
    }
    {
      float bias0 = b1e[w0 + l16];
#pragma unroll
      for (int r = 0; r < 4; ++r) {
        float v = ha[r] + bias0;
        float u_ = (0.044715f * v * v) * v + v;
        float tq = __expf(-1.5957691216057308f * u_);
        hl[(quad * 4 + r) * 40 + l16] = f2bf(v * __builtin_amdgcn_rcpf(1.0f + tq));
      }
    }
    ha = (f32x4){0.f, 0.f, 0.f, 0.f};
#pragma unroll
    for (int kk = 0; kk < 8; ++kk) {
      bf16x8 bB = *reinterpret_cast<const bf16x8*>(l1 + ((kk * 2 + 1) * 64 + lane) * 8);
      ha = __builtin_amdgcn_mfma_f32_16x16x32_bf16(afr[kk], bB, ha, 0, 0, 0);
    }
    {
      float bias1 = b1e[w0 + 16 + l16];
#pragma unroll
      for (int r = 0; r < 4; ++r) {
        float v = ha[r] + bias1;
        float u_ = (0.044715f * v * v) * v + v;
        float tq = __expf(-1.5957691216057308f * u_);
        hl[(quad * 4 + r) * 40 + 16 + l16] = f2bf(v * __builtin_amdgcn_rcpf(1.0f + tq));
      }
    }
    bf16x8 a2 = *reinterpret_cast<const bf16x8*>(hl + l16 * 40 + quad * 8);

    // GEMM2: y[16 rows x 256] += h[16 x 32] @ W2chunk[32 x 256]
#pragma unroll
    for (int ct = 0; ct < 16; ++ct) {
      bf16x8 b = *reinterpret_cast<const bf16x8*>(l2 + (ct * 64 + lane) * 8);
      acc[ct] = __builtin_amdgcn_mfma_f32_16x16x32_bf16(a2, b, acc[ct], 0, 0, 0);
    }
  }

  // epilogue: +b2, masked scatter store
  const float* b2e = b2 + e * 256;
  float bl[16];
#pragma unroll
  for (int ct = 0; ct < 16; ++ct) bl[ct] = b2e[ct * 16 + l16];
#pragma unroll
  for (int r = 0; r < 4; ++r) {
    int m = wave * 16 + quad * 4 + r;
    if (start + m < n_e) {
      float* orow = out + (size_t)prs[m] * 256;
#pragma unroll
      for (int ct = 0; ct < 16; ++ct)
        orow[ct * 16 + l16] = acc[ct][r] + bl[ct];
    }
  }
}

extern "C" void kernel_launch(void* const* d_in, const int* in_sizes, int n_in,
                              void* d_out, int out_size, void* d_ws, size_t ws_size,
                              hipStream_t stream) {
  const float* x  = (const float*)d_in[0];
  const float* rw = (const float*)d_in[1];
  const float* W1 = (const float*)d_in[2];
  const float* b1 = (const float*)d_in[3];
  const float* W2 = (const float*)d_in[4];
  const float* b2 = (const float*)d_in[5];
  const int* eids = (const int*)d_in[6];
  float* out = (float*)d_out;

  char* ws = (char*)d_ws;
  ushort_t* xn  = (ushort_t*)(ws);              // 16,777,216 B
  ushort_t* w1f = (ushort_t*)(ws + 16777216);   //  4,194,304 B
  ushort_t* w2f = (ushort_t*)(ws + 20971520);   //  4,194,304 B
  int* cnt      = (int*)(ws + 25165824);        //  256 B (8 used)
  int* lists    = (int*)(ws + 25166080);        //  2,097,152 B

  hipMemsetAsync(cnt, 0, 8 * sizeof(int), stream);
  rmsnorm_cast<<<8192, 256, 0, stream>>>(x, rw, xn);
  pack_w<<<512, 256, 0, stream>>>(W1, W2, w1f, w2f);
  route_pairs<<<256, 256, 0, stream>>>(eids, cnt, lists);
  moe_mlp<<<519, 512, 0, stream>>>(xn, w1f, w2f, b1, b2, cnt, lists, out);
}